// Round 2
// baseline (440.607 us; speedup 1.0000x reference)
//
#include <hip/hip_runtime.h>
#include <math.h>

// Problem constants (fixed by the reference file)
constexpr int G    = 256;   // N_GRAPHS
constexpr int EMB  = 64;
constexpr int ERBF = 16;

typedef __attribute__((ext_vector_type(8))) short bf16x8;
typedef __attribute__((ext_vector_type(4))) float f32x4;

// fp32 -> bf16 (round-to-nearest-even), bit-level
static __device__ __forceinline__ short bf16_rne(float f) {
    union { float f; unsigned u; } v; v.f = f;
    unsigned r = (v.u + 0x7FFFu + ((v.u >> 16) & 1u)) >> 16;
    return (short)r;
}

// ---------------------------------------------------------------------------
// Fused kernel: per-block prep of M = W2 diag(W_out) W_rbf^T (redundant per
// block, L2-hit reads), then barrier-free MFMA loop over 16-edge tiles.
//   H[16x64] = E_tile @ W1                       (8 mfma, C-layout)
//   V[16x64] = rbf_tile(pad K->32) @ M^T         (4 mfma, SAME C-layout)
//   score_e  = sum_p silu(H[e][p]) * V[e][p]
// Round-2 changes vs round 1:
//   * __launch_bounds__(256,4) + grid 1024 restored: 16 waves/CU. Round 1's
//     (256,3)/768 cut TLP on a latency-hiding-bound streaming loop (+5us).
//   * edge_emb / rbf loads are NONTEMPORAL (single-use streams; keep L2 for
//     the batch[] gather table). rbf load re-branched to q<2 so each row is
//     fetched exactly once (branchless form + nt would double rbf traffic).
//   * everything else (fused prep_M, early gather issue, transposed partial)
//     kept from round 1 (measured neutral).
// ---------------------------------------------------------------------------
__global__ __launch_bounds__(256, 4) void edge_kernel(
    const float* __restrict__ edge_emb,   // [ne][64]
    const int*   __restrict__ edge_src,   // row 0 of edge_index, [ne]
    const float* __restrict__ dvec,       // [ne][3]
    const int*   __restrict__ batch,      // [n_nodes]
    const float* __restrict__ rbf,        // [ne][16]
    const float* __restrict__ W1,         // [64][64]
    const float* __restrict__ W2,         // [64][64]
    const float* __restrict__ W_rbf,      // [16][64]
    const float* __restrict__ W_out,      // [64]
    float* __restrict__ partial,          // [G][nblk*8]  (transposed!)
    int ne, int nblk)
{
    __shared__ float accs[G * 9];         // 6 sym + count, stride 9 (bank spread)
    __shared__ float Msh[EMB * ERBF];     // folded M[64][16]

    const int tid  = threadIdx.x;
    const int w    = tid >> 6;
    const int lane = tid & 63;
    const int q    = lane >> 4;   // quad 0..3 (k-chunk selector)
    const int col  = lane & 15;   // m / n index

    for (int i = tid; i < G * 9; i += 256) accs[i] = 0.f;

    // ---- folded prep_M: thread t computes 4 consecutive entries of M ----
    {
        int idx0 = tid * 4;
        int p  = idx0 >> 4;           // all 4 entries share row p
        int k0 = idx0 & 15;           // k0 in {0,4,8,12}
        float m0 = 0.f, m1 = 0.f, m2 = 0.f, m3 = 0.f;
        for (int j = 0; j < EMB; ++j) {
            float wj = W2[p * EMB + j] * W_out[j];
            m0 = fmaf(wj, W_rbf[(k0 + 0) * EMB + j], m0);
            m1 = fmaf(wj, W_rbf[(k0 + 1) * EMB + j], m1);
            m2 = fmaf(wj, W_rbf[(k0 + 2) * EMB + j], m2);
            m3 = fmaf(wj, W_rbf[(k0 + 3) * EMB + j], m3);
        }
        Msh[idx0 + 0] = m0; Msh[idx0 + 1] = m1;
        Msh[idx0 + 2] = m2; Msh[idx0 + 3] = m3;
    }
    __syncthreads();   // Msh ready + accs zeroed before any atomics

    // ---- one-time: W1 fragments (B-layout: lane holds B[k=c*32+q*8+j][n]) ----
    bf16x8 w1f[4][2];
#pragma unroll
    for (int nt = 0; nt < 4; ++nt)
#pragma unroll
        for (int c = 0; c < 2; ++c) {
            bf16x8 wv;
#pragma unroll
            for (int j = 0; j < 8; ++j)
                wv[j] = bf16_rne(W1[(c * 32 + q * 8 + j) * EMB + nt * 16 + col]);
            w1f[nt][c] = wv;
        }
    // ---- M^T fragments for V = rbf @ M^T:  B[k][p] = M[p][k], k>=16 -> 0 ----
    bf16x8 mtf[4];
#pragma unroll
    for (int nt = 0; nt < 4; ++nt) {
        bf16x8 mv;
#pragma unroll
        for (int j = 0; j < 8; ++j) {
            int k = q * 8 + j;
            mv[j] = (k < ERBF) ? bf16_rne(Msh[(nt * 16 + col) * ERBF + k]) : (short)0;
        }
        mtf[nt] = mv;
    }

    const long estep = (long)nblk * 4 * 16;   // edges per grid iteration
    for (long e0 = ((long)blockIdx.x * 4 + w) * 16; e0 < ne; e0 += estep) {
        const long erow = e0 + col;                       // this lane's edge row
        const long erc  = (erow < ne) ? erow : (long)(ne - 1);   // clamped

        // ---- early: independent part of the gather chain (16 lanes) ----
        const long esc = e0 + q * 4 + col;     // scatter edge for this lane
        const bool sok = (col < 4) && (esc < ne);
        int src = 0; float dx = 0.f, dy = 0.f, dz = 0.f;
        if (col < 4) {
            long ec = (esc < ne) ? esc : (long)(ne - 1);
            src = edge_src[ec];
            size_t de = (size_t)ec * 3;
            dx = dvec[de]; dy = dvec[de + 1]; dz = dvec[de + 2];
        }

        // ---- streaming loads, nontemporal (single-use; don't pollute L2) ----
        const f32x4* rowe = (const f32x4*)(edge_emb + (size_t)erc * EMB + q * 8);
        f32x4 a00 = __builtin_nontemporal_load(rowe);
        f32x4 a01 = __builtin_nontemporal_load(rowe + 1);
        f32x4 a10 = __builtin_nontemporal_load(rowe + 8);   // +32 floats
        f32x4 a11 = __builtin_nontemporal_load(rowe + 9);
        f32x4 r0 = {0.f, 0.f, 0.f, 0.f}, r1 = {0.f, 0.f, 0.f, 0.f};
        if (q < 2) {   // each rbf row fetched exactly once (q0: 0-7, q1: 8-15)
            const f32x4* rowr = (const f32x4*)(rbf + (size_t)erc * ERBF + q * 8);
            r0 = __builtin_nontemporal_load(rowr);
            r1 = __builtin_nontemporal_load(rowr + 1);
        }

        // ---- dependent gather AFTER the big loads (waits only on edge_src) ----
        int gidx = 0;
        if (col < 4) gidx = batch[src];

        // ---- convert to bf16 fragments ----
        bf16x8 af0, af1, rf;
        af0[0] = bf16_rne(a00[0]); af0[1] = bf16_rne(a00[1]);
        af0[2] = bf16_rne(a00[2]); af0[3] = bf16_rne(a00[3]);
        af0[4] = bf16_rne(a01[0]); af0[5] = bf16_rne(a01[1]);
        af0[6] = bf16_rne(a01[2]); af0[7] = bf16_rne(a01[3]);
        af1[0] = bf16_rne(a10[0]); af1[1] = bf16_rne(a10[1]);
        af1[2] = bf16_rne(a10[2]); af1[3] = bf16_rne(a10[3]);
        af1[4] = bf16_rne(a11[0]); af1[5] = bf16_rne(a11[1]);
        af1[6] = bf16_rne(a11[2]); af1[7] = bf16_rne(a11[3]);
        rf[0] = bf16_rne(r0[0]); rf[1] = bf16_rne(r0[1]);
        rf[2] = bf16_rne(r0[2]); rf[3] = bf16_rne(r0[3]);
        rf[4] = bf16_rne(r1[0]); rf[5] = bf16_rne(r1[1]);
        rf[6] = bf16_rne(r1[2]); rf[7] = bf16_rne(r1[3]);

        // ---- H = E @ W1 ;  V = rbf @ M^T  (independent MFMA chains) ----
        f32x4 hacc[4], vacc[4];
#pragma unroll
        for (int nt = 0; nt < 4; ++nt) {
            f32x4 z = {0.f, 0.f, 0.f, 0.f};
            z = __builtin_amdgcn_mfma_f32_16x16x32_bf16(af0, w1f[nt][0], z, 0, 0, 0);
            z = __builtin_amdgcn_mfma_f32_16x16x32_bf16(af1, w1f[nt][1], z, 0, 0, 0);
            hacc[nt] = z;
            f32x4 zv = {0.f, 0.f, 0.f, 0.f};
            vacc[nt] = __builtin_amdgcn_mfma_f32_16x16x32_bf16(rf, mtf[nt], zv, 0, 0, 0);
        }

        // ---- score partials: lane(q,col) holds (e=q*4+r, p=nt*16+col) ----
        float sc[4];
#pragma unroll
        for (int r = 0; r < 4; ++r) {
            float acc = 0.f;
#pragma unroll
            for (int nt = 0; nt < 4; ++nt) {
                float x = hacc[nt][r];
                float s = x * __builtin_amdgcn_rcpf(1.f + __expf(-x));
                acc = fmaf(s, vacc[nt][r], acc);
            }
            sc[r] = acc;
        }
#pragma unroll
        for (int m = 1; m < 16; m <<= 1) {
#pragma unroll
            for (int r = 0; r < 4; ++r) sc[r] += __shfl_xor(sc[r], m);
        }

        // ---- scatter: geometry + graph id were prefetched at tile top ----
        if (sok) {
            float s = sc[col];
            float nrm = sqrtf(dx * dx + dy * dy + dz * dz);
            float cc = s / nrm;
            float* a = &accs[gidx * 9];
            atomicAdd(a + 0, cc * dx * dx);
            atomicAdd(a + 1, cc * dx * dy);
            atomicAdd(a + 2, cc * dx * dz);
            atomicAdd(a + 3, cc * dy * dy);
            atomicAdd(a + 4, cc * dy * dz);
            atomicAdd(a + 5, cc * dz * dz);
            atomicAdd(a + 6, 1.0f);
        }
        // no barrier: waves are fully independent until the final flush
    }

    __syncthreads();
    // ---- flush per-block bins TRANSPOSED: partial[g][b*8] so the reducer
    //      reads contiguously. Scattered 32B writes are fire-and-forget. ----
    {
        int g = tid;  // 256 threads == 256 graphs
        float* a = &accs[g * 9];
        float4 p0 = {a[0], a[1], a[2], a[3]};
        float4 p1 = {a[4], a[5], a[6], 0.f};
        float* outp = partial + (size_t)g * ((size_t)nblk * 8) + (size_t)blockIdx.x * 8;
        ((float4*)outp)[0] = p0;
        ((float4*)outp)[1] = p1;
    }
}

// ---------------------------------------------------------------------------
// Reduce: block g reads its CONTIGUOUS row partial[g][0 .. nblk*8), divides
// by count, mirrors to 3x3.
// ---------------------------------------------------------------------------
__global__ __launch_bounds__(256) void reduce_kernel(
    const float* __restrict__ partial, float* __restrict__ out, int nblk)
{
    int g = blockIdx.x;
    __shared__ float red[256][8];
    float loc[8];
#pragma unroll
    for (int c = 0; c < 8; ++c) loc[c] = 0.f;

    const float* base = partial + (size_t)g * ((size_t)nblk * 8);
    for (int b = threadIdx.x; b < nblk; b += 256) {
        const float4* p = (const float4*)(base + (size_t)b * 8);
        float4 v0 = p[0], v1 = p[1];
        loc[0] += v0.x; loc[1] += v0.y; loc[2] += v0.z; loc[3] += v0.w;
        loc[4] += v1.x; loc[5] += v1.y; loc[6] += v1.z; loc[7] += v1.w;
    }
#pragma unroll
    for (int c = 0; c < 8; ++c) red[threadIdx.x][c] = loc[c];
    __syncthreads();

    for (int off = 128; off >= 1; off >>= 1) {
        if (threadIdx.x < off) {
#pragma unroll
            for (int c = 0; c < 8; ++c)
                red[threadIdx.x][c] += red[threadIdx.x + off][c];
        }
        __syncthreads();
    }

    if (threadIdx.x == 0) {
        float cnt = red[0][6];
        float inv = (cnt > 0.f) ? (1.f / cnt) : 0.f;
        float xx = red[0][0] * inv, xy = red[0][1] * inv, xz = red[0][2] * inv;
        float yy = red[0][3] * inv, yz = red[0][4] * inv, zz = red[0][5] * inv;
        float* o = out + g * 9;
        o[0] = xx; o[1] = xy; o[2] = xz;
        o[3] = xy; o[4] = yy; o[5] = yz;
        o[6] = xz; o[7] = yz; o[8] = zz;
    }
}

// ---------------------------------------------------------------------------
extern "C" void kernel_launch(void* const* d_in, const int* in_sizes, int n_in,
                              void* d_out, int out_size, void* d_ws, size_t ws_size,
                              hipStream_t stream) {
    const float* edge_emb   = (const float*)d_in[0];
    const int*   edge_index = (const int*)  d_in[1];  // [2][ne], row 0 = src
    const float* dvec       = (const float*)d_in[2];
    // d_in[3] lattice: unused by the reference computation
    const int*   batch      = (const int*)  d_in[4];
    const float* rbf        = (const float*)d_in[5];
    const float* W1         = (const float*)d_in[6];
    const float* W2         = (const float*)d_in[7];
    const float* W_rbf      = (const float*)d_in[8];
    const float* W_out      = (const float*)d_in[9];
    float* out = (float*)d_out;

    int ne = in_sizes[0] / EMB;

    // ws layout: per-block partials only (prep_M folded into edge_kernel).
    float* partial = (float*)d_ws;
    int nblk = (int)(ws_size / (G * 8 * sizeof(float)));
    int tiles = (ne + 63) / 64;
    if (nblk > 1024)  nblk = 1024;   // 4 blocks/CU at 256 thr, <=128 VGPR
    if (nblk > tiles) nblk = tiles;
    if (nblk < 1)     nblk = 1;

    edge_kernel<<<nblk, 256, 0, stream>>>(edge_emb, edge_index, dvec, batch,
                                          rbf, W1, W2, W_rbf, W_out,
                                          partial, ne, nblk);
    reduce_kernel<<<G, 256, 0, stream>>>(partial, out, nblk);
}

// Round 3
// 425.943 us; speedup vs baseline: 1.0344x; 1.0344x over previous
//
#include <hip/hip_runtime.h>
#include <math.h>

// Problem constants (fixed by the reference file)
constexpr int G    = 256;   // N_GRAPHS
constexpr int EMB  = 64;
constexpr int ERBF = 16;

typedef __attribute__((ext_vector_type(8))) short bf16x8;
typedef __attribute__((ext_vector_type(4))) float f32x4;

// fp32 -> bf16 (round-to-nearest-even), bit-level
static __device__ __forceinline__ short bf16_rne(float f) {
    union { float f; unsigned u; } v; v.f = f;
    unsigned r = (v.u + 0x7FFFu + ((v.u >> 16) & 1u)) >> 16;
    return (short)r;
}

// ---------------------------------------------------------------------------
// Kernel 1: fold W2, W_out, W_rbf into M[64][16]:
//   M[p][k] = sum_j W2[p][j] * W_out[j] * W_rbf[k][j]
// so that score_e = silu(e @ W1) @ M @ rbf_e
// ---------------------------------------------------------------------------
__global__ void prep_M_kernel(const float* __restrict__ W2,
                              const float* __restrict__ W_rbf,
                              const float* __restrict__ W_out,
                              float* __restrict__ M) {
    int t = blockIdx.x * blockDim.x + threadIdx.x;
    if (t >= EMB * ERBF) return;
    int p = t >> 4;
    int k = t & 15;
    float acc = 0.f;
    for (int j = 0; j < EMB; ++j)
        acc = fmaf(W2[p * EMB + j] * W_out[j], W_rbf[k * EMB + j], acc);
    M[p * ERBF + k] = acc;
}

// ---------------------------------------------------------------------------
// Kernel 2 (MFMA, barrier-free loop): per wave, independent tiles of 16 edges.
//   H[16x64] = E_tile @ W1                       (8 mfma, C-layout)
//   V[16x64] = rbf_tile(pad K->32) @ M^T         (4 mfma, SAME C-layout)
//   score_e  = sum_p silu(H[e][p]) * V[e][p]     (in-lane dot over nt,
//                                                 shfl_xor butterfly over col)
//   scatter  = score/|d| * d d^T  into per-graph LDS bins (stride 9, coprime
//              with 32 banks; batch_edge is random -> stride 8 would 4-bank-alias)
// NOTE (rounds 1-2 post-mortem): occupancy must stay at (256,4)/grid 1024 —
// dropping to 3 blocks/CU cost +5us. Nontemporal loads cost +13us (nt forfeits
// L2/L3 on the 16B-of-32B interleaved row access; each 64B line is shared by
// two load instructions). Gather-hoist / fused prep_M / transposed reducer all
// measured neutral. This file is the empirical best (427.9us) verbatim.
// ---------------------------------------------------------------------------
__global__ __launch_bounds__(256, 4) void edge_kernel(
    const float* __restrict__ edge_emb,   // [ne][64]
    const int*   __restrict__ edge_src,   // row 0 of edge_index, [ne]
    const float* __restrict__ dvec,       // [ne][3]
    const int*   __restrict__ batch,      // [n_nodes]
    const float* __restrict__ rbf,        // [ne][16]
    const float* __restrict__ W1,         // [64][64]
    const float* __restrict__ M,          // [64][16]
    float* __restrict__ partial,          // [nblk][G*8]
    int ne, int nblk)
{
    __shared__ float accs[G * 9];         // 6 sym + count, stride 9 (bank spread)

    const int tid  = threadIdx.x;
    const int w    = tid >> 6;
    const int lane = tid & 63;
    const int q    = lane >> 4;   // quad 0..3 (k-chunk selector)
    const int col  = lane & 15;   // m / n index

    for (int i = tid; i < G * 9; i += 256) accs[i] = 0.f;

    // ---- one-time: W1 fragments (B-layout: lane holds B[k=c*32+q*8+j][n]) ----
    bf16x8 w1f[4][2];
#pragma unroll
    for (int nt = 0; nt < 4; ++nt)
#pragma unroll
        for (int c = 0; c < 2; ++c) {
            bf16x8 wv;
#pragma unroll
            for (int j = 0; j < 8; ++j)
                wv[j] = bf16_rne(W1[(c * 32 + q * 8 + j) * EMB + nt * 16 + col]);
            w1f[nt][c] = wv;
        }
    // ---- M^T fragments for V = rbf @ M^T:  B[k][p] = M[p][k], k>=16 -> 0 ----
    bf16x8 mtf[4];
#pragma unroll
    for (int nt = 0; nt < 4; ++nt) {
        bf16x8 mv;
#pragma unroll
        for (int j = 0; j < 8; ++j) {
            int k = q * 8 + j;
            mv[j] = (k < ERBF) ? bf16_rne(M[(nt * 16 + col) * ERBF + k]) : (short)0;
        }
        mtf[nt] = mv;
    }
    __syncthreads();   // accs zeroed before any atomics

    const long estep = (long)nblk * 4 * 16;   // edges per grid iteration
    for (long e0 = ((long)blockIdx.x * 4 + w) * 16; e0 < ne; e0 += estep) {
        const long erow  = e0 + col;          // this lane's edge row (m index)
        const bool rowok = (erow < ne);

        // ---- A fragments straight from global (bf16 convert in-reg) ----
        bf16x8 af[2];
#pragma unroll
        for (int c = 0; c < 2; ++c) {
            bf16x8 a;
            if (rowok) {
                const float4* p = (const float4*)(edge_emb + (size_t)erow * EMB + c * 32 + q * 8);
                float4 v0 = p[0], v1 = p[1];
                a[0] = bf16_rne(v0.x); a[1] = bf16_rne(v0.y);
                a[2] = bf16_rne(v0.z); a[3] = bf16_rne(v0.w);
                a[4] = bf16_rne(v1.x); a[5] = bf16_rne(v1.y);
                a[6] = bf16_rne(v1.z); a[7] = bf16_rne(v1.w);
            } else {
#pragma unroll
                for (int j = 0; j < 8; ++j) a[j] = 0;
            }
            af[c] = a;
        }
        // ---- rbf A-fragment (K padded 16->32: quads 2,3 are zero) ----
        bf16x8 rf;
        if (q < 2 && rowok) {
            const float4* p = (const float4*)(rbf + (size_t)erow * ERBF + q * 8);
            float4 v0 = p[0], v1 = p[1];
            rf[0] = bf16_rne(v0.x); rf[1] = bf16_rne(v0.y);
            rf[2] = bf16_rne(v0.z); rf[3] = bf16_rne(v0.w);
            rf[4] = bf16_rne(v1.x); rf[5] = bf16_rne(v1.y);
            rf[6] = bf16_rne(v1.z); rf[7] = bf16_rne(v1.w);
        } else {
#pragma unroll
            for (int j = 0; j < 8; ++j) rf[j] = 0;
        }

        // ---- H = E @ W1 ;  V = rbf @ M^T  (independent MFMA chains) ----
        f32x4 hacc[4], vacc[4];
#pragma unroll
        for (int nt = 0; nt < 4; ++nt) {
            f32x4 z = {0.f, 0.f, 0.f, 0.f};
            z = __builtin_amdgcn_mfma_f32_16x16x32_bf16(af[0], w1f[nt][0], z, 0, 0, 0);
            z = __builtin_amdgcn_mfma_f32_16x16x32_bf16(af[1], w1f[nt][1], z, 0, 0, 0);
            hacc[nt] = z;
            f32x4 zv = {0.f, 0.f, 0.f, 0.f};
            vacc[nt] = __builtin_amdgcn_mfma_f32_16x16x32_bf16(rf, mtf[nt], zv, 0, 0, 0);
        }

        // ---- score partials: lane(q,col) holds (e=q*4+r, p=nt*16+col) ----
        float sc[4];
#pragma unroll
        for (int r = 0; r < 4; ++r) {
            float acc = 0.f;
#pragma unroll
            for (int nt = 0; nt < 4; ++nt) {
                float x = hacc[nt][r];
                float s = x * __builtin_amdgcn_rcpf(1.f + __expf(-x));
                acc = fmaf(s, vacc[nt][r], acc);
            }
            sc[r] = acc;
        }
#pragma unroll
        for (int m = 1; m < 16; m <<= 1) {
#pragma unroll
            for (int r = 0; r < 4; ++r) sc[r] += __shfl_xor(sc[r], m);
        }

        // ---- geometry + scatter: lane with col<4 owns edge q*4+col ----
        if (col < 4) {
            long e = e0 + q * 4 + col;
            if (e < ne) {
                float s = sc[col];
                int   g = batch[edge_src[e]];
                size_t de = (size_t)e * 3;
                float dx = dvec[de], dy = dvec[de + 1], dz = dvec[de + 2];
                float nrm = sqrtf(dx * dx + dy * dy + dz * dz);
                float cc = s / nrm;
                float* a = &accs[g * 9];
                atomicAdd(a + 0, cc * dx * dx);
                atomicAdd(a + 1, cc * dx * dy);
                atomicAdd(a + 2, cc * dx * dz);
                atomicAdd(a + 3, cc * dy * dy);
                atomicAdd(a + 4, cc * dy * dz);
                atomicAdd(a + 5, cc * dz * dz);
                atomicAdd(a + 6, 1.0f);
            }
        }
        // no barrier: waves are fully independent until the final flush
    }

    __syncthreads();
    // ---- flush per-block bins (stride 9 -> stride 8 for the reducer) ----
    float* outp = partial + (size_t)blockIdx.x * (G * 8);
    {
        int g = tid;  // 256 threads == 256 graphs
        float* a = &accs[g * 9];
        float4 p0 = {a[0], a[1], a[2], a[3]};
        float4 p1 = {a[4], a[5], a[6], 0.f};
        ((float4*)(outp + g * 8))[0] = p0;
        ((float4*)(outp + g * 8))[1] = p1;
    }
}

// ---------------------------------------------------------------------------
// Kernel 3: reduce per-block partials, divide by count, mirror to 3x3.
// ---------------------------------------------------------------------------
__global__ __launch_bounds__(256) void reduce_kernel(
    const float* __restrict__ partial, float* __restrict__ out, int nblk)
{
    int g = blockIdx.x;
    __shared__ float red[256][8];
    float loc[8];
#pragma unroll
    for (int c = 0; c < 8; ++c) loc[c] = 0.f;

    for (int b = threadIdx.x; b < nblk; b += 256) {
        const float4* p = (const float4*)(partial + (size_t)b * (G * 8) + g * 8);
        float4 v0 = p[0], v1 = p[1];
        loc[0] += v0.x; loc[1] += v0.y; loc[2] += v0.z; loc[3] += v0.w;
        loc[4] += v1.x; loc[5] += v1.y; loc[6] += v1.z; loc[7] += v1.w;
    }
#pragma unroll
    for (int c = 0; c < 8; ++c) red[threadIdx.x][c] = loc[c];
    __syncthreads();

    for (int off = 128; off >= 1; off >>= 1) {
        if (threadIdx.x < off) {
#pragma unroll
            for (int c = 0; c < 8; ++c)
                red[threadIdx.x][c] += red[threadIdx.x + off][c];
        }
        __syncthreads();
    }

    if (threadIdx.x == 0) {
        float cnt = red[0][6];
        float inv = (cnt > 0.f) ? (1.f / cnt) : 0.f;
        float xx = red[0][0] * inv, xy = red[0][1] * inv, xz = red[0][2] * inv;
        float yy = red[0][3] * inv, yz = red[0][4] * inv, zz = red[0][5] * inv;
        float* o = out + g * 9;
        o[0] = xx; o[1] = xy; o[2] = xz;
        o[3] = xy; o[4] = yy; o[5] = yz;
        o[6] = xz; o[7] = yz; o[8] = zz;
    }
}

// ---------------------------------------------------------------------------
extern "C" void kernel_launch(void* const* d_in, const int* in_sizes, int n_in,
                              void* d_out, int out_size, void* d_ws, size_t ws_size,
                              hipStream_t stream) {
    const float* edge_emb   = (const float*)d_in[0];
    const int*   edge_index = (const int*)  d_in[1];  // [2][ne], row 0 = src
    const float* dvec       = (const float*)d_in[2];
    // d_in[3] lattice: unused by the reference computation
    const int*   batch      = (const int*)  d_in[4];
    const float* rbf        = (const float*)d_in[5];
    const float* W1         = (const float*)d_in[6];
    const float* W2         = (const float*)d_in[7];
    const float* W_rbf      = (const float*)d_in[8];
    const float* W_out      = (const float*)d_in[9];
    float* out = (float*)d_out;

    int ne = in_sizes[0] / EMB;

    // ws layout: [0, 4096): M (64x16). [4096, ...): per-block partials (G*8 fl).
    float* M = (float*)d_ws;
    float* partial = (float*)((char*)d_ws + 4096);
    size_t avail = (ws_size > 4096) ? (ws_size - 4096) : 0;
    int nblk = (int)(avail / (G * 8 * sizeof(float)));
    int tiles = (ne + 63) / 64;
    if (nblk > 1024)  nblk = 1024;   // 4 blocks/CU at 256 thr, <=128 VGPR
    if (nblk > tiles) nblk = tiles;
    if (nblk < 1)     nblk = 1;

    prep_M_kernel<<<4, 256, 0, stream>>>(W2, W_rbf, W_out, M);
    edge_kernel<<<nblk, 256, 0, stream>>>(edge_emb, edge_index, dvec, batch,
                                          rbf, W1, M, partial, ne, nblk);
    reduce_kernel<<<G, 256, 0, stream>>>(partial, out, nblk);
}